// Round 8
// baseline (970.743 us; speedup 1.0000x reference)
//
#include <hip/hip_runtime.h>

// ============================================================================
// Cosine-sim top-5 weighted gather, N=16384, D=256.
//   sim = normalize(A) @ normalize(A)^T ; top5 per row; out = mean(w^2 * A[idx])
//
// R7: R6 + three MFMA-pipe-bubble fixes:
//  (1) MFMA issue order = dependency-distance-4 (hi across 4 accs, then lo)
//  (2) s_setprio(1) around the MFMA cluster (waves free-run -> role diversity)
//  (3) next-jt kc0 j-frags prefetched into regs before the topk phase
// 2-term split-bf16 (hi_j*hi_i + hi_j*lo_i) MFMA GEMM; i-panel in LDS.
// Merge -> top-8/range -> fp64 rescore of top-8 -> weights^2 gather.
// ============================================================================

#define N_ROWS 16384
#define DIM 256
#define RANGES 4              // j-split of the grid
#define CANDS 32              // 4 ranges * 8 candidates

using bf16x8 = __attribute__((ext_vector_type(8))) short;   // 8 bf16 (4 VGPRs)
using f32x16 = __attribute__((ext_vector_type(16))) float;  // 32x32 acc

static __device__ __forceinline__ unsigned short f32_bf16_rne(float f) {
  unsigned u = __float_as_uint(f);
  u += 0x7fffu + ((u >> 16) & 1u);      // round-to-nearest-even (no NaN inputs)
  return (unsigned short)(u >> 16);
}

// branchless insert into ascending sorted q[0..4]:
// max(q[p], min(k, q[p+1])) == v_med3_f32(k, q[p], q[p+1]).
// Inserting k <= q[0] is a NO-OP — safe to execute on non-inserting lanes.
static __device__ __forceinline__ void ins5(float q[5], float k) {
  const float q0 = __builtin_amdgcn_fmed3f(k, q[0], q[1]);
  const float q1 = __builtin_amdgcn_fmed3f(k, q[1], q[2]);
  const float q2 = __builtin_amdgcn_fmed3f(k, q[2], q[3]);
  const float q3 = __builtin_amdgcn_fmed3f(k, q[3], q[4]);
  q[4] = fmaxf(q[4], k);
  q[0] = q0; q[1] = q1; q[2] = q2; q[3] = q3;
}

// conditional sorted insert (merge phases only; not perf-critical)
static __device__ __forceinline__ void insert8(float tv[8], int ti[8], float v, int j) {
#pragma unroll
  for (int p = 0; p < 7; ++p) {
    const bool shift = (tv[p + 1] < v);
    const bool put   = !shift && (tv[p] < v);
    const float nv = shift ? tv[p + 1] : (put ? v : tv[p]);
    const int   ni = shift ? ti[p + 1] : (put ? j : ti[p]);
    tv[p] = nv; ti[p] = ni;
  }
  if (tv[7] < v) { tv[7] = v; ti[7] = j; }
}

// ---------------------------------------------------------------------------
// Kernel 1: fp64 row norms; normalized features as bf16 hi/lo in MFMA-packed
// layout: elem(row,k) -> [row>>5][k>>4][(k>>3)&1][row&31][k&7].
// ---------------------------------------------------------------------------
__global__ __launch_bounds__(256) void prep_kernel(
    const float* __restrict__ feat,
    unsigned short* __restrict__ phi, unsigned short* __restrict__ plo,
    double* __restrict__ invn) {
  const int tid = threadIdx.x;
  const int sub = tid >> 5;
  const int l32 = tid & 31;
  const int row = blockIdx.x * 8 + sub;

  const float4 a = *reinterpret_cast<const float4*>(feat + (size_t)row * DIM + l32 * 8);
  const float4 b = *reinterpret_cast<const float4*>(feat + (size_t)row * DIM + l32 * 8 + 4);
  double s = (double)a.x * a.x + (double)a.y * a.y + (double)a.z * a.z + (double)a.w * a.w +
             (double)b.x * b.x + (double)b.y * b.y + (double)b.z * b.z + (double)b.w * b.w;
#pragma unroll
  for (int m = 16; m >= 1; m >>= 1) s += __shfl_xor(s, m);
  const double inv = 1.0 / sqrt(s);
  if (l32 == 0) invn[row] = inv;

  float nf[8] = {a.x, a.y, a.z, a.w, b.x, b.y, b.z, b.w};
  unsigned hi[8], lo[8];
#pragma unroll
  for (int e = 0; e < 8; ++e) {
    const float x  = (float)((double)nf[e] * inv);
    const unsigned short h = f32_bf16_rne(x);
    const float hf = __uint_as_float(((unsigned)h) << 16);
    hi[e] = h;
    lo[e] = f32_bf16_rne(x - hf);
  }
  const size_t off = (size_t)(row >> 5) * 8192 + (size_t)(l32 >> 1) * 512 +
                     (size_t)(l32 & 1) * 256 + (size_t)(row & 31) * 8;
  uint4 uh, ul;
  uh.x = hi[0] | (hi[1] << 16); uh.y = hi[2] | (hi[3] << 16);
  uh.z = hi[4] | (hi[5] << 16); uh.w = hi[6] | (hi[7] << 16);
  ul.x = lo[0] | (lo[1] << 16); ul.y = lo[2] | (lo[3] << 16);
  ul.z = lo[4] | (lo[5] << 16); ul.w = lo[6] | (lo[7] << 16);
  *reinterpret_cast<uint4*>(phi + off) = uh;
  *reinterpret_cast<uint4*>(plo + off) = ul;
}

// ---------------------------------------------------------------------------
// Kernel 2: fused 2-term split-bf16 GEMM + branch-filtered packed-key top-5.
// Block: 8 waves, 512 thr. All waves share the block's 64 i-rows (hi+lo in
// LDS, staged once); wave w owns a 64-j strip per jt-tile (512 j per tile).
// D[j][i]: lane's 16 acc regs belong to ONE query row -> register queues.
// Key = f32 sim, low 9 mantissa bits replaced by (jt<<5)|(r<<1)|jf.
// ---------------------------------------------------------------------------
__global__ __launch_bounds__(512, 4) void sim_topk_kernel(
    const unsigned short* __restrict__ phi, const unsigned short* __restrict__ plo,
    float* __restrict__ cval, int* __restrict__ cidx) {
  __shared__ __align__(16) union SharedU {
    struct { unsigned short h[2][8192]; unsigned short l[2][8192]; } p;  // 64 KB
    float sval[80][64];                                                  // 20 KB
  } sh;

  const int tid  = threadIdx.x;
  const int wave = tid >> 6;       // 0..7
  const int lane = tid & 63;
  const int half = lane >> 5;
  const int iblk = blockIdx.x;
  const int range = blockIdx.y;
  const int lo8  = lane * 8;

  // ---- stage i-panel (2 row-panels x hi/lo, 64 KB) into LDS ----
  {
    const uint4* shi = reinterpret_cast<const uint4*>(phi + (size_t)iblk * 16384);
    const uint4* slo = reinterpret_cast<const uint4*>(plo + (size_t)iblk * 16384);
    uint4* dhi = reinterpret_cast<uint4*>(&sh.p.h[0][0]);
    uint4* dlo = reinterpret_cast<uint4*>(&sh.p.l[0][0]);
#pragma unroll
    for (int r = 0; r < 4; ++r) {
      dhi[tid + r * 512] = shi[tid + r * 512];
      dlo[tid + r * 512] = slo[tid + r * 512];
    }
  }
  __syncthreads();

  float tv0[5], tv1[5];
#pragma unroll
  for (int c = 0; c < 5; ++c) { tv0[c] = -1e30f; tv1[c] = -1e30f; }

  // prefetch jt0 kc0 j-frags
  const unsigned short* jp0 = phi + (size_t)((range * 4096 + wave * 64) >> 5) * 8192 + lo8;
  bf16x8 pj0 = *reinterpret_cast<const bf16x8*>(jp0);
  bf16x8 pj1 = *reinterpret_cast<const bf16x8*>(jp0 + 8192);

  for (int jt = 0; jt < 8; ++jt) {
    const int jbase = range * 4096 + jt * 512 + wave * 64;
    const unsigned short* jp = phi + (size_t)(jbase >> 5) * 8192 + lo8;
    // next jt's kc0 pointer (wraps to jt0; harmless extra prefetch on last)
    const int jbn = range * 4096 + ((jt + 1) & 7) * 512 + wave * 64;
    const unsigned short* jpn = phi + (size_t)(jbn >> 5) * 8192 + lo8;

    f32x16 acc00, acc01, acc10, acc11;   // [jf][if]
#pragma unroll
    for (int r = 0; r < 16; ++r) { acc00[r] = 0.f; acc01[r] = 0.f; acc10[r] = 0.f; acc11[r] = 0.f; }

    // ---- kc0: uses prefetched j-frags (issued before previous topk) ----
    {
      const bf16x8 b0h = *reinterpret_cast<const bf16x8*>(&sh.p.h[0][lo8]);
      const bf16x8 b1h = *reinterpret_cast<const bf16x8*>(&sh.p.h[1][lo8]);
      const bf16x8 b0l = *reinterpret_cast<const bf16x8*>(&sh.p.l[0][lo8]);
      const bf16x8 b1l = *reinterpret_cast<const bf16x8*>(&sh.p.l[1][lo8]);
      __builtin_amdgcn_s_setprio(1);
      // dependency-distance-4 order: hi across 4 accs, then lo across 4 accs
      acc00 = __builtin_amdgcn_mfma_f32_32x32x16_bf16(pj0, b0h, acc00, 0, 0, 0);
      acc01 = __builtin_amdgcn_mfma_f32_32x32x16_bf16(pj0, b1h, acc01, 0, 0, 0);
      acc10 = __builtin_amdgcn_mfma_f32_32x32x16_bf16(pj1, b0h, acc10, 0, 0, 0);
      acc11 = __builtin_amdgcn_mfma_f32_32x32x16_bf16(pj1, b1h, acc11, 0, 0, 0);
      acc00 = __builtin_amdgcn_mfma_f32_32x32x16_bf16(pj0, b0l, acc00, 0, 0, 0);
      acc01 = __builtin_amdgcn_mfma_f32_32x32x16_bf16(pj0, b1l, acc01, 0, 0, 0);
      acc10 = __builtin_amdgcn_mfma_f32_32x32x16_bf16(pj1, b0l, acc10, 0, 0, 0);
      acc11 = __builtin_amdgcn_mfma_f32_32x32x16_bf16(pj1, b1l, acc11, 0, 0, 0);
      __builtin_amdgcn_s_setprio(0);
    }

#pragma unroll 2
    for (int kc = 1; kc < 16; ++kc) {
      const int ks = kc * 512;
      const bf16x8 aj0 = *reinterpret_cast<const bf16x8*>(jp + ks);          // j hi, panel 0
      const bf16x8 aj1 = *reinterpret_cast<const bf16x8*>(jp + 8192 + ks);   // j hi, panel 1
      const bf16x8 b0h = *reinterpret_cast<const bf16x8*>(&sh.p.h[0][ks + lo8]);
      const bf16x8 b1h = *reinterpret_cast<const bf16x8*>(&sh.p.h[1][ks + lo8]);
      const bf16x8 b0l = *reinterpret_cast<const bf16x8*>(&sh.p.l[0][ks + lo8]);
      const bf16x8 b1l = *reinterpret_cast<const bf16x8*>(&sh.p.l[1][ks + lo8]);
      __builtin_amdgcn_s_setprio(1);
      // sim ~= hi_j*hi_i + hi_j*lo_i   (err = <lo_j, x_i> ~ 7e-5 rms)
      acc00 = __builtin_amdgcn_mfma_f32_32x32x16_bf16(aj0, b0h, acc00, 0, 0, 0);
      acc01 = __builtin_amdgcn_mfma_f32_32x32x16_bf16(aj0, b1h, acc01, 0, 0, 0);
      acc10 = __builtin_amdgcn_mfma_f32_32x32x16_bf16(aj1, b0h, acc10, 0, 0, 0);
      acc11 = __builtin_amdgcn_mfma_f32_32x32x16_bf16(aj1, b1h, acc11, 0, 0, 0);
      acc00 = __builtin_amdgcn_mfma_f32_32x32x16_bf16(aj0, b0l, acc00, 0, 0, 0);
      acc01 = __builtin_amdgcn_mfma_f32_32x32x16_bf16(aj0, b1l, acc01, 0, 0, 0);
      acc10 = __builtin_amdgcn_mfma_f32_32x32x16_bf16(aj1, b0l, acc10, 0, 0, 0);
      acc11 = __builtin_amdgcn_mfma_f32_32x32x16_bf16(aj1, b1l, acc11, 0, 0, 0);
      __builtin_amdgcn_s_setprio(0);
    }

    // prefetch next jt's kc0 j-frags — latency hides under the topk phase
    pj0 = *reinterpret_cast<const bf16x8*>(jpn);
    pj1 = *reinterpret_cast<const bf16x8*>(jpn + 8192);

    // ---- branch-filtered packed-key top-5 update ----
    const unsigned msk = 0xFFFFFE00u;
#pragma unroll
    for (int r = 0; r < 16; ++r) {
      const unsigned c0 = (unsigned)((jt << 5) | (r << 1));
      { const float v = acc00[r];
        if (__any(v > tv0[0]))
          ins5(tv0, __uint_as_float((__float_as_uint(v) & msk) | c0)); }
      { const float v = acc01[r];
        if (__any(v > tv1[0]))
          ins5(tv1, __uint_as_float((__float_as_uint(v) & msk) | c0)); }
      { const float v = acc10[r];
        if (__any(v > tv0[0]))
          ins5(tv0, __uint_as_float((__float_as_uint(v) & msk) | (c0 | 1u))); }
      { const float v = acc11[r];
        if (__any(v > tv1[0]))
          ins5(tv1, __uint_as_float((__float_as_uint(v) & msk) | (c0 | 1u))); }
    }
    // no barrier: waves free-run; MFMA/VALU phases overlap across waves
  }

  // ---- merge 16 queues x 5 keys per row via LDS (aliased over i-panel) ----
  __syncthreads();   // all waves done reading sh.p before sval overwrites it
  {
    const int slot = (wave * 2 + half) * 5;
    const int r0 = (lane & 31);
    const int r1 = 32 + (lane & 31);
#pragma unroll
    for (int c = 0; c < 5; ++c) {
      sh.sval[slot + c][r0] = tv0[c];
      sh.sval[slot + c][r1] = tv1[c];
    }
  }
  __syncthreads();
  if (tid < 64) {
    float bv[8]; int bi[8];
#pragma unroll
    for (int c = 0; c < 8; ++c) { bv[c] = -1e30f; bi[c] = 0; }
    for (int wv = 0; wv < 8; ++wv)
#pragma unroll
      for (int hh = 0; hh < 2; ++hh)
#pragma unroll
        for (int c = 0; c < 5; ++c) {
          const float v = sh.sval[(wv * 2 + hh) * 5 + c][tid];
          if (v > bv[0]) {
            const unsigned code = __float_as_uint(v) & 0x1FFu;
            const int jf = (int)(code & 1u);
            const int r  = (int)((code >> 1) & 15u);
            const int jt = (int)(code >> 5);
            const int jl = (r & 3) + 8 * (r >> 2) + 4 * hh;
            const int j  = range * 4096 + jt * 512 + wv * 64 + jf * 32 + jl;
            insert8(bv, bi, v, j);
          }
        }
    const size_t base = (size_t)(iblk * 64 + tid) * CANDS + range * 8;
#pragma unroll
    for (int c = 0; c < 8; ++c) { cval[base + c] = bv[c]; cidx[base + c] = bi[c]; }
  }
}

// ---------------------------------------------------------------------------
// Kernel 3: per row (one wave): merge 32 candidates -> top-8 by stage-1 key,
// fp64 rescore, top-5, weights^2, fused weighted gather.
// ---------------------------------------------------------------------------
__global__ __launch_bounds__(256) void finalize_kernel(
    const float* __restrict__ feat, const double* __restrict__ invn,
    const float* __restrict__ cval, const int* __restrict__ cidx,
    float* __restrict__ out) {
  const int wave = threadIdx.x >> 6, lane = threadIdx.x & 63;
  const int row = blockIdx.x * 4 + wave;

  float v = -1e30f; int id = -1;
  if (lane < 32) {
    v  = cval[(size_t)row * CANDS + lane];
    id = cidx[(size_t)row * CANDS + lane];
  }
  int sel[8];
#pragma unroll
  for (int c = 0; c < 8; ++c) {
    float mv = v; int mi = id;
#pragma unroll
    for (int m = 32; m >= 1; m >>= 1) {
      const float ov = __shfl_xor(mv, m); const int oi = __shfl_xor(mi, m);
      if (ov > mv || (ov == mv && oi > mi)) { mv = ov; mi = oi; }
    }
    sel[c] = mi;
    if (id == mi) v = -1e30f;
  }

  const float4 q = *reinterpret_cast<const float4*>(feat + (size_t)row * DIM + lane * 4);
  const double inv_i = invn[row];
  double sims[8];
#pragma unroll
  for (int c = 0; c < 8; ++c) {
    const int j = sel[c];
    const float4 f = *reinterpret_cast<const float4*>(feat + (size_t)j * DIM + lane * 4);
    double s = (double)q.x * f.x + (double)q.y * f.y + (double)q.z * f.z + (double)q.w * f.w;
#pragma unroll
    for (int m = 32; m >= 1; m >>= 1) s += __shfl_xor(s, m);
    sims[c] = s * inv_i * invn[j];
  }

  unsigned usedmask = 0;
  float4 o; o.x = o.y = o.z = o.w = 0.f;
#pragma unroll
  for (int t = 0; t < 5; ++t) {
    double best = -1e30; int bc = 0, bj = 0;
#pragma unroll
    for (int c = 0; c < 8; ++c)
      if (!((usedmask >> c) & 1u) && sims[c] > best) { best = sims[c]; bc = c; bj = sel[c]; }
    usedmask |= (1u << bc);
    const float w2 = (float)(best * best);
    const float4 f = *reinterpret_cast<const float4*>(feat + (size_t)bj * DIM + lane * 4);
    o.x += w2 * f.x; o.y += w2 * f.y; o.z += w2 * f.z; o.w += w2 * f.w;
  }
  o.x *= 0.2f; o.y *= 0.2f; o.z *= 0.2f; o.w *= 0.2f;
  *reinterpret_cast<float4*>(out + (size_t)row * DIM + lane * 4) = o;
}

// ---------------------------------------------------------------------------
extern "C" void kernel_launch(void* const* d_in, const int* in_sizes, int n_in,
                              void* d_out, int out_size, void* d_ws, size_t ws_size,
                              hipStream_t stream) {
  const float* feat = (const float*)d_in[0];
  char* ws = (char*)d_ws;

  // phi (8.39 MB) lives in d_out (16.7 MB) until finalize overwrites it.
  unsigned short* phi = (unsigned short*)d_out;
  unsigned short* plo = (unsigned short*)(ws + 0);            // 8,388,608 B
  double*        invn = (double*)(ws + 8388608);              //   131,072 B
  float*        cvalp = (float*)(ws + 8519680);               // 2,097,152 B
  int*          cidxp = (int*)(ws + 10616832);                // 2,097,152 B
  float*          out = (float*)d_out;

  prep_kernel<<<N_ROWS / 8, 256, 0, stream>>>(feat, phi, plo, invn);
  dim3 g2(N_ROWS / 64, RANGES);
  sim_topk_kernel<<<g2, 512, 0, stream>>>(phi, plo, cvalp, cidxp);
  finalize_kernel<<<N_ROWS / 4, 256, 0, stream>>>(feat, invn, cvalp, cidxp, out);
}

// Round 11
// 378.547 us; speedup vs baseline: 2.5644x; 2.5644x over previous
//
#include <hip/hip_runtime.h>

// ============================================================================
// Cosine-sim top-5 weighted gather, N=16384, D=256.
//   sim = normalize(A) @ normalize(A)^T ; top5 per row; out = mean(w^2 * A[idx])
//
// R9 (resubmit; R10 bench was an infra failure): R6 (passed, 267us sim_topk)
// + s_setprio(1/0) around each kc's MFMA cluster — register-neutral T5 test.
// R8's MFMA reorder is REVERTED (tripped the determinism tripwire with NaN).
// Rules learned: at (512,4) any added live state spills (R4/R5/R7);
// MFMA source order stays pairwise (R8).
// 2-term split-bf16 (hi_j*hi_i + hi_j*lo_i) MFMA GEMM; i-panel in LDS.
// Merge -> top-8/range -> fp64 rescore of top-8 -> weights^2 gather.
// ============================================================================

#define N_ROWS 16384
#define DIM 256
#define RANGES 4              // j-split of the grid
#define CANDS 32              // 4 ranges * 8 candidates

using bf16x8 = __attribute__((ext_vector_type(8))) short;   // 8 bf16 (4 VGPRs)
using f32x16 = __attribute__((ext_vector_type(16))) float;  // 32x32 acc

static __device__ __forceinline__ unsigned short f32_bf16_rne(float f) {
  unsigned u = __float_as_uint(f);
  u += 0x7fffu + ((u >> 16) & 1u);      // round-to-nearest-even (no NaN inputs)
  return (unsigned short)(u >> 16);
}

// branchless insert into ascending sorted q[0..4]:
// max(q[p], min(k, q[p+1])) == v_med3_f32(k, q[p], q[p+1]).
// Inserting k <= q[0] is a NO-OP — safe to execute on non-inserting lanes.
static __device__ __forceinline__ void ins5(float q[5], float k) {
  const float q0 = __builtin_amdgcn_fmed3f(k, q[0], q[1]);
  const float q1 = __builtin_amdgcn_fmed3f(k, q[1], q[2]);
  const float q2 = __builtin_amdgcn_fmed3f(k, q[2], q[3]);
  const float q3 = __builtin_amdgcn_fmed3f(k, q[3], q[4]);
  q[4] = fmaxf(q[4], k);
  q[0] = q0; q[1] = q1; q[2] = q2; q[3] = q3;
}

// conditional sorted insert (merge phases only; not perf-critical)
static __device__ __forceinline__ void insert8(float tv[8], int ti[8], float v, int j) {
#pragma unroll
  for (int p = 0; p < 7; ++p) {
    const bool shift = (tv[p + 1] < v);
    const bool put   = !shift && (tv[p] < v);
    const float nv = shift ? tv[p + 1] : (put ? v : tv[p]);
    const int   ni = shift ? ti[p + 1] : (put ? j : ti[p]);
    tv[p] = nv; ti[p] = ni;
  }
  if (tv[7] < v) { tv[7] = v; ti[7] = j; }
}

// ---------------------------------------------------------------------------
// Kernel 1: fp64 row norms; normalized features as bf16 hi/lo in MFMA-packed
// layout: elem(row,k) -> [row>>5][k>>4][(k>>3)&1][row&31][k&7].
// ---------------------------------------------------------------------------
__global__ __launch_bounds__(256) void prep_kernel(
    const float* __restrict__ feat,
    unsigned short* __restrict__ phi, unsigned short* __restrict__ plo,
    double* __restrict__ invn) {
  const int tid = threadIdx.x;
  const int sub = tid >> 5;
  const int l32 = tid & 31;
  const int row = blockIdx.x * 8 + sub;

  const float4 a = *reinterpret_cast<const float4*>(feat + (size_t)row * DIM + l32 * 8);
  const float4 b = *reinterpret_cast<const float4*>(feat + (size_t)row * DIM + l32 * 8 + 4);
  double s = (double)a.x * a.x + (double)a.y * a.y + (double)a.z * a.z + (double)a.w * a.w +
             (double)b.x * b.x + (double)b.y * b.y + (double)b.z * b.z + (double)b.w * b.w;
#pragma unroll
  for (int m = 16; m >= 1; m >>= 1) s += __shfl_xor(s, m);
  const double inv = 1.0 / sqrt(s);
  if (l32 == 0) invn[row] = inv;

  float nf[8] = {a.x, a.y, a.z, a.w, b.x, b.y, b.z, b.w};
  unsigned hi[8], lo[8];
#pragma unroll
  for (int e = 0; e < 8; ++e) {
    const float x  = (float)((double)nf[e] * inv);
    const unsigned short h = f32_bf16_rne(x);
    const float hf = __uint_as_float(((unsigned)h) << 16);
    hi[e] = h;
    lo[e] = f32_bf16_rne(x - hf);
  }
  const size_t off = (size_t)(row >> 5) * 8192 + (size_t)(l32 >> 1) * 512 +
                     (size_t)(l32 & 1) * 256 + (size_t)(row & 31) * 8;
  uint4 uh, ul;
  uh.x = hi[0] | (hi[1] << 16); uh.y = hi[2] | (hi[3] << 16);
  uh.z = hi[4] | (hi[5] << 16); uh.w = hi[6] | (hi[7] << 16);
  ul.x = lo[0] | (lo[1] << 16); ul.y = lo[2] | (lo[3] << 16);
  ul.z = lo[4] | (lo[5] << 16); ul.w = lo[6] | (lo[7] << 16);
  *reinterpret_cast<uint4*>(phi + off) = uh;
  *reinterpret_cast<uint4*>(plo + off) = ul;
}

// ---------------------------------------------------------------------------
// Kernel 2: fused 2-term split-bf16 GEMM + branch-filtered packed-key top-5.
// Block: 8 waves, 512 thr. All waves share the block's 64 i-rows (hi+lo in
// LDS, staged once); wave w owns a 64-j strip per jt-tile (512 j per tile).
// D[j][i]: lane's 16 acc regs belong to ONE query row -> register queues.
// Key = f32 sim, low 9 mantissa bits replaced by (jt<<5)|(r<<1)|jf.
// ---------------------------------------------------------------------------
__global__ __launch_bounds__(512, 4) void sim_topk_kernel(
    const unsigned short* __restrict__ phi, const unsigned short* __restrict__ plo,
    float* __restrict__ cval, int* __restrict__ cidx) {
  __shared__ __align__(16) union SharedU {
    struct { unsigned short h[2][8192]; unsigned short l[2][8192]; } p;  // 64 KB
    float sval[80][64];                                                  // 20 KB
  } sh;

  const int tid  = threadIdx.x;
  const int wave = tid >> 6;       // 0..7
  const int lane = tid & 63;
  const int half = lane >> 5;
  const int iblk = blockIdx.x;
  const int range = blockIdx.y;
  const int lo8  = lane * 8;

  // ---- stage i-panel (2 row-panels x hi/lo, 64 KB) into LDS ----
  {
    const uint4* shi = reinterpret_cast<const uint4*>(phi + (size_t)iblk * 16384);
    const uint4* slo = reinterpret_cast<const uint4*>(plo + (size_t)iblk * 16384);
    uint4* dhi = reinterpret_cast<uint4*>(&sh.p.h[0][0]);
    uint4* dlo = reinterpret_cast<uint4*>(&sh.p.l[0][0]);
#pragma unroll
    for (int r = 0; r < 4; ++r) {
      dhi[tid + r * 512] = shi[tid + r * 512];
      dlo[tid + r * 512] = slo[tid + r * 512];
    }
  }
  __syncthreads();

  float tv0[5], tv1[5];
#pragma unroll
  for (int c = 0; c < 5; ++c) { tv0[c] = -1e30f; tv1[c] = -1e30f; }

  for (int jt = 0; jt < 8; ++jt) {
    const int jbase = range * 4096 + jt * 512 + wave * 64;
    const unsigned short* jp = phi + (size_t)(jbase >> 5) * 8192 + lo8;

    f32x16 acc00, acc01, acc10, acc11;   // [jf][if]
#pragma unroll
    for (int r = 0; r < 16; ++r) { acc00[r] = 0.f; acc01[r] = 0.f; acc10[r] = 0.f; acc11[r] = 0.f; }

#pragma unroll 2
    for (int kc = 0; kc < 16; ++kc) {
      const int ks = kc * 512;
      const bf16x8 aj0 = *reinterpret_cast<const bf16x8*>(jp + ks);          // j hi, panel 0
      const bf16x8 aj1 = *reinterpret_cast<const bf16x8*>(jp + 8192 + ks);   // j hi, panel 1
      const bf16x8 b0h = *reinterpret_cast<const bf16x8*>(&sh.p.h[0][ks + lo8]);
      const bf16x8 b1h = *reinterpret_cast<const bf16x8*>(&sh.p.h[1][ks + lo8]);
      const bf16x8 b0l = *reinterpret_cast<const bf16x8*>(&sh.p.l[0][ks + lo8]);
      const bf16x8 b1l = *reinterpret_cast<const bf16x8*>(&sh.p.l[1][ks + lo8]);
      // sim ~= hi_j*hi_i + hi_j*lo_i   (err = <lo_j, x_i> ~ 7e-5 rms)
      // R6's pairwise order (R8's reorder tripped the determinism tripwire).
      __builtin_amdgcn_s_setprio(1);
      acc00 = __builtin_amdgcn_mfma_f32_32x32x16_bf16(aj0, b0h, acc00, 0, 0, 0);
      acc00 = __builtin_amdgcn_mfma_f32_32x32x16_bf16(aj0, b0l, acc00, 0, 0, 0);
      acc01 = __builtin_amdgcn_mfma_f32_32x32x16_bf16(aj0, b1h, acc01, 0, 0, 0);
      acc01 = __builtin_amdgcn_mfma_f32_32x32x16_bf16(aj0, b1l, acc01, 0, 0, 0);
      acc10 = __builtin_amdgcn_mfma_f32_32x32x16_bf16(aj1, b0h, acc10, 0, 0, 0);
      acc10 = __builtin_amdgcn_mfma_f32_32x32x16_bf16(aj1, b0l, acc10, 0, 0, 0);
      acc11 = __builtin_amdgcn_mfma_f32_32x32x16_bf16(aj1, b1h, acc11, 0, 0, 0);
      acc11 = __builtin_amdgcn_mfma_f32_32x32x16_bf16(aj1, b1l, acc11, 0, 0, 0);
      __builtin_amdgcn_s_setprio(0);
    }

    // ---- branch-filtered packed-key top-5 update ----
    const unsigned msk = 0xFFFFFE00u;
#pragma unroll
    for (int r = 0; r < 16; ++r) {
      const unsigned c0 = (unsigned)((jt << 5) | (r << 1));
      { const float v = acc00[r];
        if (__any(v > tv0[0]))
          ins5(tv0, __uint_as_float((__float_as_uint(v) & msk) | c0)); }
      { const float v = acc01[r];
        if (__any(v > tv1[0]))
          ins5(tv1, __uint_as_float((__float_as_uint(v) & msk) | c0)); }
      { const float v = acc10[r];
        if (__any(v > tv0[0]))
          ins5(tv0, __uint_as_float((__float_as_uint(v) & msk) | (c0 | 1u))); }
      { const float v = acc11[r];
        if (__any(v > tv1[0]))
          ins5(tv1, __uint_as_float((__float_as_uint(v) & msk) | (c0 | 1u))); }
    }
    // no barrier: waves free-run; MFMA/VALU phases overlap across waves
  }

  // ---- merge 16 queues x 5 keys per row via LDS (aliased over i-panel) ----
  __syncthreads();   // all waves done reading sh.p before sval overwrites it
  {
    const int slot = (wave * 2 + half) * 5;
    const int r0 = (lane & 31);
    const int r1 = 32 + (lane & 31);
#pragma unroll
    for (int c = 0; c < 5; ++c) {
      sh.sval[slot + c][r0] = tv0[c];
      sh.sval[slot + c][r1] = tv1[c];
    }
  }
  __syncthreads();
  if (tid < 64) {
    float bv[8]; int bi[8];
#pragma unroll
    for (int c = 0; c < 8; ++c) { bv[c] = -1e30f; bi[c] = 0; }
    for (int wv = 0; wv < 8; ++wv)
#pragma unroll
      for (int hh = 0; hh < 2; ++hh)
#pragma unroll
        for (int c = 0; c < 5; ++c) {
          const float v = sh.sval[(wv * 2 + hh) * 5 + c][tid];
          if (v > bv[0]) {
            const unsigned code = __float_as_uint(v) & 0x1FFu;
            const int jf = (int)(code & 1u);
            const int r  = (int)((code >> 1) & 15u);
            const int jt = (int)(code >> 5);
            const int jl = (r & 3) + 8 * (r >> 2) + 4 * hh;
            const int j  = range * 4096 + jt * 512 + wv * 64 + jf * 32 + jl;
            insert8(bv, bi, v, j);
          }
        }
    const size_t base = (size_t)(iblk * 64 + tid) * CANDS + range * 8;
#pragma unroll
    for (int c = 0; c < 8; ++c) { cval[base + c] = bv[c]; cidx[base + c] = bi[c]; }
  }
}

// ---------------------------------------------------------------------------
// Kernel 3: per row (one wave): merge 32 candidates -> top-8 by stage-1 key,
// fp64 rescore, top-5, weights^2, fused weighted gather.
// ---------------------------------------------------------------------------
__global__ __launch_bounds__(256) void finalize_kernel(
    const float* __restrict__ feat, const double* __restrict__ invn,
    const float* __restrict__ cval, const int* __restrict__ cidx,
    float* __restrict__ out) {
  const int wave = threadIdx.x >> 6, lane = threadIdx.x & 63;
  const int row = blockIdx.x * 4 + wave;

  float v = -1e30f; int id = -1;
  if (lane < 32) {
    v  = cval[(size_t)row * CANDS + lane];
    id = cidx[(size_t)row * CANDS + lane];
  }
  int sel[8];
#pragma unroll
  for (int c = 0; c < 8; ++c) {
    float mv = v; int mi = id;
#pragma unroll
    for (int m = 32; m >= 1; m >>= 1) {
      const float ov = __shfl_xor(mv, m); const int oi = __shfl_xor(mi, m);
      if (ov > mv || (ov == mv && oi > mi)) { mv = ov; mi = oi; }
    }
    sel[c] = mi;
    if (id == mi) v = -1e30f;
  }

  const float4 q = *reinterpret_cast<const float4*>(feat + (size_t)row * DIM + lane * 4);
  const double inv_i = invn[row];
  double sims[8];
#pragma unroll
  for (int c = 0; c < 8; ++c) {
    const int j = sel[c];
    const float4 f = *reinterpret_cast<const float4*>(feat + (size_t)j * DIM + lane * 4);
    double s = (double)q.x * f.x + (double)q.y * f.y + (double)q.z * f.z + (double)q.w * f.w;
#pragma unroll
    for (int m = 32; m >= 1; m >>= 1) s += __shfl_xor(s, m);
    sims[c] = s * inv_i * invn[j];
  }

  unsigned usedmask = 0;
  float4 o; o.x = o.y = o.z = o.w = 0.f;
#pragma unroll
  for (int t = 0; t < 5; ++t) {
    double best = -1e30; int bc = 0, bj = 0;
#pragma unroll
    for (int c = 0; c < 8; ++c)
      if (!((usedmask >> c) & 1u) && sims[c] > best) { best = sims[c]; bc = c; bj = sel[c]; }
    usedmask |= (1u << bc);
    const float w2 = (float)(best * best);
    const float4 f = *reinterpret_cast<const float4*>(feat + (size_t)bj * DIM + lane * 4);
    o.x += w2 * f.x; o.y += w2 * f.y; o.z += w2 * f.z; o.w += w2 * f.w;
  }
  o.x *= 0.2f; o.y *= 0.2f; o.z *= 0.2f; o.w *= 0.2f;
  *reinterpret_cast<float4*>(out + (size_t)row * DIM + lane * 4) = o;
}

// ---------------------------------------------------------------------------
extern "C" void kernel_launch(void* const* d_in, const int* in_sizes, int n_in,
                              void* d_out, int out_size, void* d_ws, size_t ws_size,
                              hipStream_t stream) {
  const float* feat = (const float*)d_in[0];
  char* ws = (char*)d_ws;

  // phi (8.39 MB) lives in d_out (16.7 MB) until finalize overwrites it.
  unsigned short* phi = (unsigned short*)d_out;
  unsigned short* plo = (unsigned short*)(ws + 0);            // 8,388,608 B
  double*        invn = (double*)(ws + 8388608);              //   131,072 B
  float*        cvalp = (float*)(ws + 8519680);               // 2,097,152 B
  int*          cidxp = (int*)(ws + 10616832);                // 2,097,152 B
  float*          out = (float*)d_out;

  prep_kernel<<<N_ROWS / 8, 256, 0, stream>>>(feat, phi, plo, invn);
  dim3 g2(N_ROWS / 64, RANGES);
  sim_topk_kernel<<<g2, 512, 0, stream>>>(phi, plo, cvalp, cidxp);
  finalize_kernel<<<N_ROWS / 4, 256, 0, stream>>>(feat, invn, cvalp, cidxp, out);
}

// Round 12
// 290.208 us; speedup vs baseline: 3.3450x; 1.3044x over previous
//
#include <hip/hip_runtime.h>

// ============================================================================
// Cosine-sim top-5 weighted gather, N=16384, D=256.
//   sim = normalize(A) @ normalize(A)^T ; top5 per row; out = mean(w^2 * A[idx])
//
// R12: 1-TERM bf16 screening GEMM (hi_j*hi_i only; screen err ~1e-4 rms vs
// top5/6 gaps ~3.5e-3) + per-range top-8 + fp64 rescore of merged top-8.
// Benefits vs R6/R9: half the MFMA work; natural source order is
// dependency-distance-4 (1 MFMA per acc per kc -> no dependent back-to-back,
// no R8-style reorder); no plo stream; LDS 32 KB -> better occupancy.
// Rules kept: no added live state at (512,4) (spills); no MFMA reorder (R8
// NaN tripwire); no setprio (R9: -5%).
// ============================================================================

#define N_ROWS 16384
#define DIM 256
#define RANGES 4              // j-split of the grid
#define CANDS 32              // 4 ranges * 8 candidates

using bf16x8 = __attribute__((ext_vector_type(8))) short;   // 8 bf16 (4 VGPRs)
using f32x16 = __attribute__((ext_vector_type(16))) float;  // 32x32 acc

static __device__ __forceinline__ unsigned short f32_bf16_rne(float f) {
  unsigned u = __float_as_uint(f);
  u += 0x7fffu + ((u >> 16) & 1u);      // round-to-nearest-even (no NaN inputs)
  return (unsigned short)(u >> 16);
}

// branchless insert into ascending sorted q[0..4]:
// max(q[p], min(k, q[p+1])) == v_med3_f32(k, q[p], q[p+1]).
// Inserting k <= q[0] is a NO-OP — safe to execute on non-inserting lanes.
static __device__ __forceinline__ void ins5(float q[5], float k) {
  const float q0 = __builtin_amdgcn_fmed3f(k, q[0], q[1]);
  const float q1 = __builtin_amdgcn_fmed3f(k, q[1], q[2]);
  const float q2 = __builtin_amdgcn_fmed3f(k, q[2], q[3]);
  const float q3 = __builtin_amdgcn_fmed3f(k, q[3], q[4]);
  q[4] = fmaxf(q[4], k);
  q[0] = q0; q[1] = q1; q[2] = q2; q[3] = q3;
}

// conditional sorted insert (merge phases only; not perf-critical)
static __device__ __forceinline__ void insert8(float tv[8], int ti[8], float v, int j) {
#pragma unroll
  for (int p = 0; p < 7; ++p) {
    const bool shift = (tv[p + 1] < v);
    const bool put   = !shift && (tv[p] < v);
    const float nv = shift ? tv[p + 1] : (put ? v : tv[p]);
    const int   ni = shift ? ti[p + 1] : (put ? j : ti[p]);
    tv[p] = nv; ti[p] = ni;
  }
  if (tv[7] < v) { tv[7] = v; ti[7] = j; }
}

// ---------------------------------------------------------------------------
// Kernel 1: fp64 row norms; normalized features as bf16 (hi only) in
// MFMA-packed layout: elem(row,k) -> [row>>5][k>>4][(k>>3)&1][row&31][k&7].
// ---------------------------------------------------------------------------
__global__ __launch_bounds__(256) void prep_kernel(
    const float* __restrict__ feat,
    unsigned short* __restrict__ phi,
    double* __restrict__ invn) {
  const int tid = threadIdx.x;
  const int sub = tid >> 5;
  const int l32 = tid & 31;
  const int row = blockIdx.x * 8 + sub;

  const float4 a = *reinterpret_cast<const float4*>(feat + (size_t)row * DIM + l32 * 8);
  const float4 b = *reinterpret_cast<const float4*>(feat + (size_t)row * DIM + l32 * 8 + 4);
  double s = (double)a.x * a.x + (double)a.y * a.y + (double)a.z * a.z + (double)a.w * a.w +
             (double)b.x * b.x + (double)b.y * b.y + (double)b.z * b.z + (double)b.w * b.w;
#pragma unroll
  for (int m = 16; m >= 1; m >>= 1) s += __shfl_xor(s, m);
  const double inv = 1.0 / sqrt(s);
  if (l32 == 0) invn[row] = inv;

  float nf[8] = {a.x, a.y, a.z, a.w, b.x, b.y, b.z, b.w};
  unsigned hi[8];
#pragma unroll
  for (int e = 0; e < 8; ++e)
    hi[e] = f32_bf16_rne((float)((double)nf[e] * inv));
  const size_t off = (size_t)(row >> 5) * 8192 + (size_t)(l32 >> 1) * 512 +
                     (size_t)(l32 & 1) * 256 + (size_t)(row & 31) * 8;
  uint4 uh;
  uh.x = hi[0] | (hi[1] << 16); uh.y = hi[2] | (hi[3] << 16);
  uh.z = hi[4] | (hi[5] << 16); uh.w = hi[6] | (hi[7] << 16);
  *reinterpret_cast<uint4*>(phi + off) = uh;
}

// ---------------------------------------------------------------------------
// Kernel 2: fused 1-term bf16 GEMM + branch-filtered packed-key top-5.
// Block: 8 waves, 512 thr. All waves share the block's 64 i-rows (hi in LDS,
// 32 KB, staged once); wave w owns a 64-j strip per jt-tile (512 j per tile).
// D[j][i]: lane's 16 acc regs belong to ONE query row -> register queues.
// Per kc: 4 MFMAs on 4 independent accs = natural dependency-distance-4.
// Key = f32 sim, low 9 mantissa bits replaced by (jt<<5)|(r<<1)|jf.
// ---------------------------------------------------------------------------
__global__ __launch_bounds__(512, 4) void sim_topk_kernel(
    const unsigned short* __restrict__ phi,
    float* __restrict__ cval, int* __restrict__ cidx) {
  __shared__ __align__(16) union SharedU {
    unsigned short h[2][8192];   // 32 KB i-panel (hi only)
    float sval[80][64];          // 20 KB merge scratch (aliased)
  } sh;

  const int tid  = threadIdx.x;
  const int wave = tid >> 6;       // 0..7
  const int lane = tid & 63;
  const int half = lane >> 5;
  const int iblk = blockIdx.x;
  const int range = blockIdx.y;
  const int lo8  = lane * 8;

  // ---- stage i-panel (2 row-panels, hi only, 32 KB) into LDS ----
  {
    const uint4* shi = reinterpret_cast<const uint4*>(phi + (size_t)iblk * 16384);
    uint4* dhi = reinterpret_cast<uint4*>(&sh.h[0][0]);
#pragma unroll
    for (int r = 0; r < 4; ++r)
      dhi[tid + r * 512] = shi[tid + r * 512];
  }
  __syncthreads();

  float tv0[5], tv1[5];
#pragma unroll
  for (int c = 0; c < 5; ++c) { tv0[c] = -1e30f; tv1[c] = -1e30f; }

  for (int jt = 0; jt < 8; ++jt) {
    const int jbase = range * 4096 + jt * 512 + wave * 64;
    const unsigned short* jp = phi + (size_t)(jbase >> 5) * 8192 + lo8;

    f32x16 acc00, acc01, acc10, acc11;   // [jf][if]
#pragma unroll
    for (int r = 0; r < 16; ++r) { acc00[r] = 0.f; acc01[r] = 0.f; acc10[r] = 0.f; acc11[r] = 0.f; }

#pragma unroll 2
    for (int kc = 0; kc < 16; ++kc) {
      const int ks = kc * 512;
      const bf16x8 aj0 = *reinterpret_cast<const bf16x8*>(jp + ks);          // j hi, panel 0
      const bf16x8 aj1 = *reinterpret_cast<const bf16x8*>(jp + 8192 + ks);   // j hi, panel 1
      const bf16x8 b0  = *reinterpret_cast<const bf16x8*>(&sh.h[0][ks + lo8]);
      const bf16x8 b1  = *reinterpret_cast<const bf16x8*>(&sh.h[1][ks + lo8]);
      // screen = hi_j * hi_i  (err ~1e-4 rms; fp64 rescore fixes selection)
      // one MFMA per acc per kc -> dependent ops are 4 apart (128 pipe-cyc)
      acc00 = __builtin_amdgcn_mfma_f32_32x32x16_bf16(aj0, b0, acc00, 0, 0, 0);
      acc01 = __builtin_amdgcn_mfma_f32_32x32x16_bf16(aj0, b1, acc01, 0, 0, 0);
      acc10 = __builtin_amdgcn_mfma_f32_32x32x16_bf16(aj1, b0, acc10, 0, 0, 0);
      acc11 = __builtin_amdgcn_mfma_f32_32x32x16_bf16(aj1, b1, acc11, 0, 0, 0);
    }

    // ---- branch-filtered packed-key top-5 update ----
    const unsigned msk = 0xFFFFFE00u;
#pragma unroll
    for (int r = 0; r < 16; ++r) {
      const unsigned c0 = (unsigned)((jt << 5) | (r << 1));
      { const float v = acc00[r];
        if (__any(v > tv0[0]))
          ins5(tv0, __uint_as_float((__float_as_uint(v) & msk) | c0)); }
      { const float v = acc01[r];
        if (__any(v > tv1[0]))
          ins5(tv1, __uint_as_float((__float_as_uint(v) & msk) | c0)); }
      { const float v = acc10[r];
        if (__any(v > tv0[0]))
          ins5(tv0, __uint_as_float((__float_as_uint(v) & msk) | (c0 | 1u))); }
      { const float v = acc11[r];
        if (__any(v > tv1[0]))
          ins5(tv1, __uint_as_float((__float_as_uint(v) & msk) | (c0 | 1u))); }
    }
    // no barrier: waves free-run; MFMA/VALU phases overlap across waves
  }

  // ---- merge 16 queues x 5 keys per row via LDS (aliased over i-panel) ----
  __syncthreads();   // all waves done reading sh.h before sval overwrites it
  {
    const int slot = (wave * 2 + half) * 5;
    const int r0 = (lane & 31);
    const int r1 = 32 + (lane & 31);
#pragma unroll
    for (int c = 0; c < 5; ++c) {
      sh.sval[slot + c][r0] = tv0[c];
      sh.sval[slot + c][r1] = tv1[c];
    }
  }
  __syncthreads();
  if (tid < 64) {
    float bv[8]; int bi[8];
#pragma unroll
    for (int c = 0; c < 8; ++c) { bv[c] = -1e30f; bi[c] = 0; }
    for (int wv = 0; wv < 8; ++wv)
#pragma unroll
      for (int hh = 0; hh < 2; ++hh)
#pragma unroll
        for (int c = 0; c < 5; ++c) {
          const float v = sh.sval[(wv * 2 + hh) * 5 + c][tid];
          if (v > bv[0]) {
            const unsigned code = __float_as_uint(v) & 0x1FFu;
            const int jf = (int)(code & 1u);
            const int r  = (int)((code >> 1) & 15u);
            const int jt = (int)(code >> 5);
            const int jl = (r & 3) + 8 * (r >> 2) + 4 * hh;
            const int j  = range * 4096 + jt * 512 + wv * 64 + jf * 32 + jl;
            insert8(bv, bi, v, j);
          }
        }
    const size_t base = (size_t)(iblk * 64 + tid) * CANDS + range * 8;
#pragma unroll
    for (int c = 0; c < 8; ++c) { cval[base + c] = bv[c]; cidx[base + c] = bi[c]; }
  }
}

// ---------------------------------------------------------------------------
// Kernel 3: per row (one wave): merge 32 candidates -> top-8 by stage-1 key,
// fp64 rescore, top-5, weights^2, fused weighted gather.
// ---------------------------------------------------------------------------
__global__ __launch_bounds__(256) void finalize_kernel(
    const float* __restrict__ feat, const double* __restrict__ invn,
    const float* __restrict__ cval, const int* __restrict__ cidx,
    float* __restrict__ out) {
  const int wave = threadIdx.x >> 6, lane = threadIdx.x & 63;
  const int row = blockIdx.x * 4 + wave;

  float v = -1e30f; int id = -1;
  if (lane < 32) {
    v  = cval[(size_t)row * CANDS + lane];
    id = cidx[(size_t)row * CANDS + lane];
  }
  int sel[8];
#pragma unroll
  for (int c = 0; c < 8; ++c) {
    float mv = v; int mi = id;
#pragma unroll
    for (int m = 32; m >= 1; m >>= 1) {
      const float ov = __shfl_xor(mv, m); const int oi = __shfl_xor(mi, m);
      if (ov > mv || (ov == mv && oi > mi)) { mv = ov; mi = oi; }
    }
    sel[c] = mi;
    if (id == mi) v = -1e30f;
  }

  const float4 q = *reinterpret_cast<const float4*>(feat + (size_t)row * DIM + lane * 4);
  const double inv_i = invn[row];
  double sims[8];
#pragma unroll
  for (int c = 0; c < 8; ++c) {
    const int j = sel[c];
    const float4 f = *reinterpret_cast<const float4*>(feat + (size_t)j * DIM + lane * 4);
    double s = (double)q.x * f.x + (double)q.y * f.y + (double)q.z * f.z + (double)q.w * f.w;
#pragma unroll
    for (int m = 32; m >= 1; m >>= 1) s += __shfl_xor(s, m);
    sims[c] = s * inv_i * invn[j];
  }

  unsigned usedmask = 0;
  float4 o; o.x = o.y = o.z = o.w = 0.f;
#pragma unroll
  for (int t = 0; t < 5; ++t) {
    double best = -1e30; int bc = 0, bj = 0;
#pragma unroll
    for (int c = 0; c < 8; ++c)
      if (!((usedmask >> c) & 1u) && sims[c] > best) { best = sims[c]; bc = c; bj = sel[c]; }
    usedmask |= (1u << bc);
    const float w2 = (float)(best * best);
    const float4 f = *reinterpret_cast<const float4*>(feat + (size_t)bj * DIM + lane * 4);
    o.x += w2 * f.x; o.y += w2 * f.y; o.z += w2 * f.z; o.w += w2 * f.w;
  }
  o.x *= 0.2f; o.y *= 0.2f; o.z *= 0.2f; o.w *= 0.2f;
  *reinterpret_cast<float4*>(out + (size_t)row * DIM + lane * 4) = o;
}

// ---------------------------------------------------------------------------
extern "C" void kernel_launch(void* const* d_in, const int* in_sizes, int n_in,
                              void* d_out, int out_size, void* d_ws, size_t ws_size,
                              hipStream_t stream) {
  const float* feat = (const float*)d_in[0];
  char* ws = (char*)d_ws;

  // phi (8.39 MB) lives in d_out (16.7 MB) until finalize overwrites it.
  unsigned short* phi = (unsigned short*)d_out;
  double*        invn = (double*)(ws + 0);                    //   131,072 B
  float*        cvalp = (float*)(ws + 131072);                // 2,097,152 B
  int*          cidxp = (int*)(ws + 2228224);                 // 2,097,152 B
  float*          out = (float*)d_out;

  prep_kernel<<<N_ROWS / 8, 256, 0, stream>>>(feat, phi, invn);
  dim3 g2(N_ROWS / 64, RANGES);
  sim_topk_kernel<<<g2, 512, 0, stream>>>(phi, cvalp, cidxp);
  finalize_kernel<<<N_ROWS / 4, 256, 0, stream>>>(feat, invn, cvalp, cidxp, out);
}